// Round 5
// baseline (96.415 us; speedup 1.0000x reference)
//
#include <hip/hip_runtime.h>
#include <hip/hip_bf16.h>

#define SEQ 394
#define EMB 300
#define EMBP 304                         // padded emb: 608 B rows -> 16B-aligned everywhere
#define NROWS (64 * SEQ)                 // 25216
#define XPTOT ((long)NROWS * EMBP)       // 7,665,664 elems
#define NCH 115                          // K-chunks of 32: 29 + 38 + 48 (Kp = 928/1216/1536 over 304-padded rows)
#define CB1 29
#define CB2 67
#define XG 2622                          // X granules actually read (69 rows x 38)
#define XGFILL 2624                      // filled granules (wave-round granularity)
#define XE (XGFILL * 8)                  // 20992 elems X region
#define PRIV 2048                        // priv W buf elems (64 filt x 32 k)

typedef __attribute__((ext_vector_type(8))) short short8;
typedef __attribute__((ext_vector_type(4))) float f32x4;

__device__ __forceinline__ unsigned short f2b(float f) {
    unsigned u = __float_as_uint(f);
    u += 0x7FFFu + ((u >> 16) & 1u);   // RNE to bf16
    return (unsigned short)(u >> 16);
}

__device__ __forceinline__ void gload_lds16(const void* g, void* l) {
    __builtin_amdgcn_global_load_lds(
        (const __attribute__((address_space(1))) void*)g,
        (__attribute__((address_space(3))) void*)l, 16, 0, 0);
}

// ---------------- pack kernels ----------------

// x fp32 [25216][300] -> xp bf16 [25216][304], cols 300..303 zero
__global__ __launch_bounds__(256)
void pack_x_kernel(const float* __restrict__ x, unsigned short* __restrict__ xp)
{
    long q = (long)blockIdx.x * 256 + threadIdx.x;       // quad index (4 elems)
    if (q >= XPTOT / 4) return;
    int row = (int)(q / 76);
    int c4  = ((int)(q - (long)row * 76)) * 4;
    ushort4 u;
    if (c4 < 300) {                                       // rows are 1200B -> float4 aligned
        float4 v = *(const float4*)(x + (long)row * 300 + c4);
        u = make_ushort4(f2b(v.x), f2b(v.y), f2b(v.z), f2b(v.w));
    } else {
        u = make_ushort4(0, 0, 0, 0);
    }
    *(ushort4*)(xp + q * 4) = u;
}

// W -> chunk-major blob [115][256 filters][32 k] bf16 over the 304-padded k-axis.
// k-local kl -> row r = kl/304, emb e = kl%304; zero where e>=300 or r>=n or beyond Kp.
__global__ __launch_bounds__(256)
void pack_w_kernel(const float* __restrict__ W1, const float* __restrict__ W2,
                   const float* __restrict__ W3, unsigned short* __restrict__ wb)
{
    int G = blockIdx.x * 256 + threadIdx.x;              // granule of 8 elems; 117760 total
    int c   = G >> 10;                                   // 1024 granules per chunk
    int rem = G & 1023;
    int f   = rem >> 2;
    int gs  = rem & 3;
    const float* Wg; int n, cb;
    if (c < CB1)      { Wg = W1; n = 3; cb = 0;   }
    else if (c < CB2) { Wg = W2; n = 4; cb = CB1; }
    else              { Wg = W3; n = 5; cb = CB2; }
    const int K = n * 300;
    const int kl = (c - cb) * 32 + gs * 8;
    unsigned short v[8];
#pragma unroll
    for (int j = 0; j < 8; ++j) {
        int kk = kl + j;
        int r  = kk / EMBP;
        int e  = kk - r * EMBP;
        v[j] = (e < 300 && r < n) ? f2b(Wg[(long)f * K + r * 300 + e]) : (unsigned short)0;
    }
    unsigned short* dst = wb + (long)G * 8;
    *(ushort4*)dst       = make_ushort4(v[0], v[1], v[2], v[3]);
    *(ushort4*)(dst + 4) = make_ushort4(v[4], v[5], v[6], v[7]);
}

// ---------------- main kernel ----------------
// Grid 448 = batch(64) x window-tile(7 of 64). Block 256 thr = 4 waves.
// Wave tile: 64 filters x 64 windows. X resident in LDS (shared, read-only after
// one prologue barrier); W streamed into PER-WAVE private double-buffers -> the
// K-loop has NO barriers; per-wave counted vmcnt(4) is a complete guarantee.

__global__ __launch_bounds__(256, 2)
void convgemm_kernel(const unsigned short* __restrict__ xp,
                     const unsigned short* __restrict__ wb,
                     const float* __restrict__ b1, const float* __restrict__ b2,
                     const float* __restrict__ b3,
                     float* __restrict__ out)
{
    __shared__ unsigned short LDS[XE + 4 * 2 * PRIV];    // 41984 + 32768 = 74752 B

    const int tid  = threadIdx.x;
    const int lane = tid & 63;
    const int wid  = tid >> 6;
    const int lr   = lane & 15, lg = lane >> 4;
    const int b    = blockIdx.x / 7;
    const int t    = blockIdx.x - b * 7;
    const int i0   = t * 64;

    // ---- prologue: fill resident X (rows b*394+i0 .., 304-strided, clamped) ----
    const unsigned short* xsrc = xp + ((long)b * SEQ + i0) * EMBP;
    const long xrem8 = XPTOT - ((long)b * SEQ + i0) * EMBP - 8;   // >= 3032, 16B-aligned+8? (mult304-8)*2B aligned 16 ✓
#pragma unroll
    for (int rd = 0; rd < 11; ++rd) {
        int gbw = rd * 256 + wid * 64;                   // wave-uniform granule base
        if (gbw < XG) {                                  // wave-uniform guard (last round partial)
            long se = (long)(gbw + lane) * 8;
            if (se > xrem8) se = xrem8;                  // clamp: junk only in masked/W-zero region
            gload_lds16(xsrc + se, &LDS[gbw * 8]);
        }
    }
    // stage W chunk 0 into own wave's buf 0
    {
        const unsigned short* ws = wb + (long)(0 * 256 + wid * 64) * 32;
        unsigned short* wd = &LDS[XE + (wid * 2 + 0) * PRIV];
#pragma unroll
        for (int j = 0; j < 4; ++j)
            gload_lds16(ws + j * 512 + lane * 8, wd + j * 512);
    }
    __syncthreads();                                      // drains all; X visible to all waves

    f32x4 acc[4][4];
#pragma unroll
    for (int i = 0; i < 4; ++i)
#pragma unroll
        for (int j = 0; j < 4; ++j)
            acc[i][j] = (f32x4)0.0f;

    const int ob0 = b * 768;
    const int af_off = lr * 32 + lg * 8;                  // within priv chunk, row-major [64][32]

    for (int br = 0; br < 3; ++br) {
        const int c0 = (br == 0) ? 0 : (br == 1) ? CB1 : CB2;
        const int c1 = (br == 0) ? CB1 : (br == 1) ? CB2 : NCH;

        for (int c = c0; c < c1; ++c) {
            // issue next chunk into the other private buffer (self-paced, no barrier)
            if (c + 1 < NCH) {
                const unsigned short* ws = wb + ((long)(c + 1) * 256 + wid * 64) * 32;
                unsigned short* wd = &LDS[XE + (wid * 2 + ((c + 1) & 1)) * PRIV];
#pragma unroll
                for (int j = 0; j < 4; ++j)
                    gload_lds16(ws + j * 512 + lane * 8, wd + j * 512);
                asm volatile("s_waitcnt vmcnt(4)" ::: "memory");   // chunk c landed; c+1 in flight
            } else {
                asm volatile("s_waitcnt vmcnt(0)" ::: "memory");
            }
            __builtin_amdgcn_sched_barrier(0);

            const unsigned short* Wc = &LDS[XE + (wid * 2 + (c & 1)) * PRIV];
            const int bxe = (c - c0) * 32;

            short8 af[4], bx[4];
#pragma unroll
            for (int mi = 0; mi < 4; ++mi)
                af[mi] = *(const short8*)&Wc[mi * 512 + af_off];          // (mi*16+lr)*32 + lg*8
#pragma unroll
            for (int ni = 0; ni < 4; ++ni)
                bx[ni] = *(const short8*)&LDS[(ni * 16 + lr) * EMBP + bxe + lg * 8];

#pragma unroll
            for (int mi = 0; mi < 4; ++mi)
#pragma unroll
                for (int ni = 0; ni < 4; ++ni)
                    acc[mi][ni] = __builtin_amdgcn_mfma_f32_16x16x32_bf16(af[mi], bx[ni], acc[mi][ni], 0, 0, 0);
        }

        // ---- branch epilogue: bias + relu + window-mask + 16-lane max + atomicMax ----
        {
            const float* bg = (br == 0) ? b1 : (br == 1) ? b2 : b3;
            const int Nw = 391 - br;
            int wlim = Nw - i0; if (wlim > 64) wlim = 64;
            const int ob = ob0 + br * 256;
#pragma unroll
            for (int mi = 0; mi < 4; ++mi) {
#pragma unroll
                for (int r = 0; r < 4; ++r) {
                    const int d = wid * 64 + mi * 16 + lg * 4 + r;    // C/D row = lg*4+r
                    const float bv = bg[d];
                    float m = 0.f;
#pragma unroll
                    for (int ni = 0; ni < 4; ++ni) {
                        int n = ni * 16 + lr;                          // C/D col = lr
                        float v = fmaxf(acc[mi][ni][r] + bv, 0.f);
                        if (n >= wlim) v = 0.f;
                        m = fmaxf(m, v);
                    }
#pragma unroll
                    for (int off = 1; off < 16; off <<= 1)
                        m = fmaxf(m, __shfl_xor(m, off));
                    if (lr == 0)
                        atomicMax((int*)(out + ob + d), __float_as_int(m));
                }
            }
#pragma unroll
            for (int i = 0; i < 4; ++i)
#pragma unroll
                for (int j = 0; j < 4; ++j)
                    acc[i][j] = (f32x4)0.0f;
        }
    }
}

// ---------------- fallback (no-workspace path) ----------------

__device__ __forceinline__ void load_chunk(const float* __restrict__ Wg,
                                           const float* __restrict__ xb,
                                           int K, int dbase, int i0, int k0, int tid,
                                           float4 wv[4], float4 xv[4])
{
#pragma unroll
    for (int i = 0; i < 4; ++i) {
        int fi  = tid + (i << 8);
        int row = fi >> 3;
        int c4  = (fi & 7) << 2;
        int col = k0 + c4;
        if (col < K)
            wv[i] = *(const float4*)(Wg + (long)(dbase + row) * K + col);
        else
            wv[i] = make_float4(0.f, 0.f, 0.f, 0.f);
        int off = (i0 + row) * EMB + col;
        int lim = SEQ * EMB - 4;
        if (off > lim) off = lim;
        xv[i] = *(const float4*)(xb + off);
    }
}

__device__ __forceinline__ void write_chunk(unsigned short (*Wb)[40],
                                            unsigned short (*Xb)[40],
                                            int tid, const float4 wv[4], const float4 xv[4])
{
#pragma unroll
    for (int i = 0; i < 4; ++i) {
        int fi  = tid + (i << 8);
        int row = fi >> 3;
        int c4  = (fi & 7) << 2;
        *(ushort4*)&Wb[row][c4] = make_ushort4(f2b(wv[i].x), f2b(wv[i].y), f2b(wv[i].z), f2b(wv[i].w));
        *(ushort4*)&Xb[row][c4] = make_ushort4(f2b(xv[i].x), f2b(xv[i].y), f2b(xv[i].z), f2b(xv[i].w));
    }
}

__global__ __launch_bounds__(256, 2)
void convmax_fallback(const float* __restrict__ x,
                      const float* __restrict__ W1, const float* __restrict__ W2,
                      const float* __restrict__ W3,
                      const float* __restrict__ b1, const float* __restrict__ b2,
                      const float* __restrict__ b3,
                      float* __restrict__ out)
{
    const int br = blockIdx.z;
    const int K  = (br == 0) ? 900 : (br == 1) ? 1200 : 1500;
    const int Nw = SEQ - 3 - br;
    const float* Wg = (br == 0) ? W1 : (br == 1) ? W2 : W3;
    const float* bg = (br == 0) ? b1 : (br == 1) ? b2 : b3;
    const int b  = blockIdx.x;
    const int mt = blockIdx.y >> 2;
    const int nt = blockIdx.y & 3;
    const int dbase = mt * 128;
    const int i0    = nt * 128;
    const float* xb = x + b * (SEQ * EMB);
    const int nch = (K + 31) >> 5;

    __shared__ unsigned short Wl[2][128][40];
    __shared__ unsigned short Xl[2][128][40];

    const int tid  = threadIdx.x;
    const int lane = tid & 63;
    const int wid  = tid >> 6;
    const int wr = wid >> 1, wc = wid & 1;
    const int lr = lane & 15, lg = lane >> 4;

    f32x4 acc[4][4];
#pragma unroll
    for (int i = 0; i < 4; ++i)
#pragma unroll
        for (int j = 0; j < 4; ++j)
            acc[i][j] = (f32x4)0.0f;

    {
        float4 wv[4], xv[4];
        load_chunk(Wg, xb, K, dbase, i0, 0, tid, wv, xv);
        write_chunk(Wl[0], Xl[0], tid, wv, xv);
    }
    __syncthreads();

    for (int c = 0; c < nch; ++c) {
        const int cur = c & 1;
        float4 wv[4], xv[4];
        const bool pf = (c + 1 < nch);
        if (pf) load_chunk(Wg, xb, K, dbase, i0, (c + 1) << 5, tid, wv, xv);

        short8 af[4], bfr[4];
#pragma unroll
        for (int mi = 0; mi < 4; ++mi)
            af[mi] = *(const short8*)&Wl[cur][wr * 64 + mi * 16 + lr][lg * 8];
#pragma unroll
        for (int ni = 0; ni < 4; ++ni)
            bfr[ni] = *(const short8*)&Xl[cur][wc * 64 + ni * 16 + lr][lg * 8];
#pragma unroll
        for (int mi = 0; mi < 4; ++mi)
#pragma unroll
            for (int ni = 0; ni < 4; ++ni)
                acc[mi][ni] = __builtin_amdgcn_mfma_f32_16x16x32_bf16(af[mi], bfr[ni], acc[mi][ni], 0, 0, 0);

        if (pf) write_chunk(Wl[cur ^ 1], Xl[cur ^ 1], tid, wv, xv);
        __syncthreads();
    }

    const int ob = b * 768 + br * 256;
#pragma unroll
    for (int mi = 0; mi < 4; ++mi) {
#pragma unroll
        for (int rI = 0; rI < 4; ++rI) {
            const int d = dbase + wr * 64 + mi * 16 + lg * 4 + rI;
            const float bv = bg[d];
            float m = 0.f;
#pragma unroll
            for (int ni = 0; ni < 4; ++ni) {
                int win = i0 + wc * 64 + ni * 16 + lr;
                float v = acc[mi][ni][rI] + bv;
                v = fmaxf(v, 0.f);
                if (win >= Nw) v = 0.f;
                m = fmaxf(m, v);
            }
#pragma unroll
            for (int off = 1; off < 16; off <<= 1)
                m = fmaxf(m, __shfl_xor(m, off));
            if (lr == 0)
                atomicMax((int*)(out + ob + d), __float_as_int(m));
        }
    }
}

// ---------------- launch ----------------

extern "C" void kernel_launch(void* const* d_in, const int* in_sizes, int n_in,
                              void* d_out, int out_size, void* d_ws, size_t ws_size,
                              hipStream_t stream) {
    const float* x  = (const float*)d_in[0];
    const float* W1 = (const float*)d_in[1];
    const float* W2 = (const float*)d_in[2];
    const float* W3 = (const float*)d_in[3];
    const float* b1 = (const float*)d_in[4];
    const float* b2 = (const float*)d_in[5];
    const float* b3 = (const float*)d_in[6];
    float* out = (float*)d_out;

    hipMemsetAsync(d_out, 0, (size_t)out_size * sizeof(float), stream);

    const long WBTOT = (long)NCH * 8192;                 // 942,080 elems
    const size_t need = (size_t)(XPTOT + WBTOT) * 2;     // ~17.2 MB

    if (ws_size >= need) {
        unsigned short* xp = (unsigned short*)d_ws;
        unsigned short* wbb = xp + XPTOT;

        pack_x_kernel<<<(int)(XPTOT / 4 / 256), 256, 0, stream>>>(x, xp);   // 7486 blocks, exact
        pack_w_kernel<<<460, 256, 0, stream>>>(W1, W2, W3, wbb);            // 117760/256, exact
        convgemm_kernel<<<448, 256, 0, stream>>>(xp, wbb, b1, b2, b3, out);
    } else {
        dim3 grid(64, 8, 3);
        convmax_fallback<<<grid, 256, 0, stream>>>(x, W1, W2, W3, b1, b2, b3, out);
    }
}

// Round 6
// 88.224 us; speedup vs baseline: 1.0928x; 1.0928x over previous
//
#include <hip/hip_runtime.h>
#include <hip/hip_bf16.h>

#define SEQ 394
#define EMB 300
#define EMBP 312                          // 624B rows: 16B-aligned AND odd multiple of 16B -> conflict-free b128
#define NROWS (64 * SEQ)                  // 25216
#define XPTOT ((long)NROWS * EMBP)        // 7,867,392 elems
#define NCHT 118                          // chunks of K=32: 30 (br0, Kp 960) + 39 (br1, 1248) + 49 (br2, 1568)
#define CBE0 29                           // last chunk idx of br0
#define CBE1 68
#define XE 36864                          // X region elems (4608 granules = 117+ rows x 312)
#define WGRAN ((long)NCHT * 1024)         // W blob granules (8 elems each)

typedef __attribute__((ext_vector_type(8))) short short8;
typedef __attribute__((ext_vector_type(4))) float f32x4;

__device__ __forceinline__ unsigned short f2b(float f) {
    unsigned u = __float_as_uint(f);
    u += 0x7FFFu + ((u >> 16) & 1u);   // RNE to bf16
    return (unsigned short)(u >> 16);
}

__device__ __forceinline__ void gload_lds16(const void* g, void* l) {
    __builtin_amdgcn_global_load_lds(
        (const __attribute__((address_space(1))) void*)g,
        (__attribute__((address_space(3))) void*)l, 16, 0, 0);
}

// ---------------- pack kernels ----------------

// x fp32 [25216][300] -> xp bf16 [25216][312], cols 300..311 zero
__global__ __launch_bounds__(256)
void pack_x_kernel(const float* __restrict__ x, unsigned short* __restrict__ xp)
{
    long q = (long)blockIdx.x * 256 + threadIdx.x;       // quad of 4 elems; 1,966,848 total (exact)
    int row = (int)(q / 78);
    int c4  = ((int)(q - (long)row * 78)) * 4;
    ushort4 u;
    if (c4 < 300) {
        float4 v = *(const float4*)(x + (long)row * 300 + c4);
        u = make_ushort4(f2b(v.x), f2b(v.y), f2b(v.z), f2b(v.w));
    } else {
        u = make_ushort4(0, 0, 0, 0);
    }
    *(ushort4*)(xp + q * 4) = u;
}

// W -> blob [chunk c][fgroup 8][32 filt][4 slots][8], over the 312-padded k-axis,
// zero past K / emb-pad; af-swizzle PRE-APPLIED: slot gs holds granule gs ^ ((f_loc>>1)&3)
__global__ __launch_bounds__(256)
void pack_w_kernel(const float* __restrict__ W1, const float* __restrict__ W2,
                   const float* __restrict__ W3, unsigned short* __restrict__ wb)
{
    int G = blockIdx.x * 256 + threadIdx.x;              // granule; 120,832 total (exact)
    int c    = G >> 10;
    int rem  = G & 1023;
    int fg   = rem >> 7;
    int floc = (rem >> 2) & 31;
    int gs   = rem & 3;
    const float* Wg; int n, cb;
    if (c <= CBE0)      { Wg = W1; n = 3; cb = 0;        }
    else if (c <= CBE1) { Wg = W2; n = 4; cb = CBE0 + 1; }
    else                { Wg = W3; n = 5; cb = CBE1 + 1; }
    const int K = n * 300;
    const int f = fg * 32 + floc;
    const int kl = (c - cb) * 32 + (gs ^ ((floc >> 1) & 3)) * 8;
    unsigned short v[8];
#pragma unroll
    for (int j = 0; j < 8; ++j) {
        int kk = kl + j;
        int r  = kk / EMBP;
        int e  = kk - r * EMBP;
        v[j] = (r < n && e < 300) ? f2b(Wg[(long)f * K + r * 300 + e]) : (unsigned short)0;
    }
    unsigned short* dst = wb + (long)G * 8;
    *(ushort4*)dst       = make_ushort4(v[0], v[1], v[2], v[3]);
    *(ushort4*)(dst + 4) = make_ushort4(v[4], v[5], v[6], v[7]);
}

// ---------------- main kernel ----------------
// Grid 256 = batch(64) x window-tile(4 of 98). 512 thr = 8 waves, wave = 32 filters x 112 windows.
// X resident in LDS once; W streamed into per-wave private 4-deep buffers (no K-loop barriers).
// Register-level pipeline: read chunk c+1 frags while MFMAing chunk c.

__global__ __launch_bounds__(512, 2)
void convgemm_kernel(const unsigned short* __restrict__ xp,
                     const unsigned short* __restrict__ wb,
                     const float* __restrict__ b1, const float* __restrict__ b2,
                     const float* __restrict__ b3,
                     float* __restrict__ out)
{
    __shared__ unsigned short LDS[XE + 8 * 4096];        // 73728B X + 65536B W = 136 KiB

    const int tid  = threadIdx.x;
    const int lane = tid & 63;
    const int wid  = tid >> 6;
    const int lr   = lane & 15, lg = lane >> 4;
    const int b    = blockIdx.x >> 2;
    const int i0   = (blockIdx.x & 3) * 98;

    // ---- stage W chunk cc into this wave's private buffer (cc&3) ----
    auto stageW = [&](int cc) {
        const unsigned short* ws = wb + ((long)(cc * 8 + wid)) * 1024 + lane * 8;
        unsigned short* wd = &LDS[XE + wid * 4096 + (cc & 3) * 1024];
        gload_lds16(ws, wd);
        gload_lds16(ws + 512, wd + 512);
    };

    // ---- prologue: fill resident X (117 rows, 4608 granules) + W chunks 0..2 ----
    {
        const long xbase = ((long)b * SEQ + i0) * EMBP;  // granule-aligned (312 = 39*8)
        const long slim  = XPTOT - 8;
#pragma unroll
        for (int rd = 0; rd < 9; ++rd) {
            int g = rd * 512 + wid * 64;                 // wave-uniform base; 9*512 = 4608 exact
            long se = xbase + (long)(g + lane) * 8;
            if (se > slim) se = slim;                    // clamp: garbage finite, masked later
            gload_lds16(xp + se, &LDS[g * 8]);
        }
    }
    stageW(0); stageW(1); stageW(2);
    asm volatile("s_waitcnt vmcnt(0)" ::: "memory");
    __builtin_amdgcn_sched_barrier(0);
    __builtin_amdgcn_s_barrier();                        // X visible to all waves
    __builtin_amdgcn_sched_barrier(0);

    f32x4 acc[2][7];
#pragma unroll
    for (int i = 0; i < 2; ++i)
#pragma unroll
        for (int j = 0; j < 7; ++j)
            acc[i][j] = (f32x4)0.0f;

    const int swz = (lg ^ ((lr >> 1) & 3)) * 8;

    auto readFrags = [&](int cc, short8 af[2], short8 bx[7]) {
        const int c0  = (cc <= CBE0) ? 0 : (cc <= CBE1) ? (CBE0 + 1) : (CBE1 + 1);
        const int bxe = (cc - c0) * 32;
        const unsigned short* Wc = &LDS[XE + wid * 4096 + (cc & 3) * 1024];
        af[0] = *(const short8*)&Wc[lr * 32 + swz];
        af[1] = *(const short8*)&Wc[(16 + lr) * 32 + swz];
#pragma unroll
        for (int ni = 0; ni < 7; ++ni)
            bx[ni] = *(const short8*)&LDS[(ni * 16 + lr) * EMBP + bxe + lg * 8];
    };

    auto doMFMA = [&](short8 af[2], short8 bx[7]) {
#pragma unroll
        for (int mi = 0; mi < 2; ++mi)
#pragma unroll
            for (int ni = 0; ni < 7; ++ni)
                acc[mi][ni] = __builtin_amdgcn_mfma_f32_16x16x32_bf16(af[mi], bx[ni], acc[mi][ni], 0, 0, 0);
    };

    auto epilogue = [&](int br) {
        const float* bg = (br == 0) ? b1 : (br == 1) ? b2 : b3;
        const int Nw = 391 - br;
        int wlim = Nw - i0; if (wlim > 112) wlim = 112;  // overlap windows 98..111 valid: max is idempotent
        const int ob = b * 768 + br * 256;
#pragma unroll
        for (int mi = 0; mi < 2; ++mi) {
#pragma unroll
            for (int r = 0; r < 4; ++r) {
                const int d = wid * 32 + mi * 16 + lg * 4 + r;
                const float bv = bg[d];
                float m = 0.f;
#pragma unroll
                for (int ni = 0; ni < 7; ++ni) {
                    int w = ni * 16 + lr;
                    float v = fmaxf(acc[mi][ni][r] + bv, 0.f);
                    if (w >= wlim) v = 0.f;
                    m = fmaxf(m, v);
                }
#pragma unroll
                for (int off = 1; off < 16; off <<= 1)
                    m = fmaxf(m, __shfl_xor(m, off));
                if (lr == 0)
                    atomicMax((int*)(out + ob + d), __float_as_int(m));
            }
        }
#pragma unroll
        for (int i = 0; i < 2; ++i)
#pragma unroll
            for (int j = 0; j < 7; ++j)
                acc[i][j] = (f32x4)0.0f;
    };

    short8 fa0[2], fb0[7], fa1[2], fb1[7];
    readFrags(0, fa0, fb0);

    for (int c = 0; c < NCHT; c += 2) {
        // ---- even sub-iter: chunk c (set0), prefetch frags c+1 (set1) ----
        if (c + 3 < NCHT) stageW(c + 3);
        if (c + 3 < NCHT)      asm volatile("s_waitcnt vmcnt(4)" ::: "memory");
        else if (c + 2 < NCHT) asm volatile("s_waitcnt vmcnt(2)" ::: "memory");
        else                   asm volatile("s_waitcnt vmcnt(0)" ::: "memory");
        __builtin_amdgcn_sched_barrier(0);
        readFrags(c + 1, fa1, fb1);                      // c+1 <= 117 always
        doMFMA(fa0, fb0);                                // compiler inserts counted lgkm for set0
        if (c == CBE1) epilogue(1);                      // 68 is even

        // ---- odd sub-iter: chunk c+1 (set1), prefetch frags c+2 (set0) ----
        const int cc = c + 1;
        if (cc + 3 < NCHT) stageW(cc + 3);
        if (cc + 3 < NCHT)      asm volatile("s_waitcnt vmcnt(4)" ::: "memory");
        else if (cc + 2 < NCHT) asm volatile("s_waitcnt vmcnt(2)" ::: "memory");
        else                    asm volatile("s_waitcnt vmcnt(0)" ::: "memory");
        __builtin_amdgcn_sched_barrier(0);
        if (cc + 1 < NCHT) readFrags(cc + 1, fa0, fb0);
        doMFMA(fa1, fb1);
        if (cc == CBE0) epilogue(0);                     // 29 is odd
        if (cc == NCHT - 1) epilogue(2);                 // 117 is odd
    }
}

// ---------------- fallback (no-workspace path) ----------------

__device__ __forceinline__ void load_chunk(const float* __restrict__ Wg,
                                           const float* __restrict__ xb,
                                           int K, int dbase, int i0, int k0, int tid,
                                           float4 wv[4], float4 xv[4])
{
#pragma unroll
    for (int i = 0; i < 4; ++i) {
        int fi  = tid + (i << 8);
        int row = fi >> 3;
        int c4  = (fi & 7) << 2;
        int col = k0 + c4;
        if (col < K)
            wv[i] = *(const float4*)(Wg + (long)(dbase + row) * K + col);
        else
            wv[i] = make_float4(0.f, 0.f, 0.f, 0.f);
        int off = (i0 + row) * EMB + col;
        int lim = SEQ * EMB - 4;
        if (off > lim) off = lim;
        xv[i] = *(const float4*)(xb + off);
    }
}

__device__ __forceinline__ void write_chunk(unsigned short (*Wb)[40],
                                            unsigned short (*Xb)[40],
                                            int tid, const float4 wv[4], const float4 xv[4])
{
#pragma unroll
    for (int i = 0; i < 4; ++i) {
        int fi  = tid + (i << 8);
        int row = fi >> 3;
        int c4  = (fi & 7) << 2;
        *(ushort4*)&Wb[row][c4] = make_ushort4(f2b(wv[i].x), f2b(wv[i].y), f2b(wv[i].z), f2b(wv[i].w));
        *(ushort4*)&Xb[row][c4] = make_ushort4(f2b(xv[i].x), f2b(xv[i].y), f2b(xv[i].z), f2b(xv[i].w));
    }
}

__global__ __launch_bounds__(256, 2)
void convmax_fallback(const float* __restrict__ x,
                      const float* __restrict__ W1, const float* __restrict__ W2,
                      const float* __restrict__ W3,
                      const float* __restrict__ b1, const float* __restrict__ b2,
                      const float* __restrict__ b3,
                      float* __restrict__ out)
{
    const int br = blockIdx.z;
    const int K  = (br == 0) ? 900 : (br == 1) ? 1200 : 1500;
    const int Nw = SEQ - 3 - br;
    const float* Wg = (br == 0) ? W1 : (br == 1) ? W2 : W3;
    const float* bg = (br == 0) ? b1 : (br == 1) ? b2 : b3;
    const int b  = blockIdx.x;
    const int mt = blockIdx.y >> 2;
    const int nt = blockIdx.y & 3;
    const int dbase = mt * 128;
    const int i0    = nt * 128;
    const float* xb = x + b * (SEQ * EMB);
    const int nch = (K + 31) >> 5;

    __shared__ unsigned short Wl[2][128][40];
    __shared__ unsigned short Xl[2][128][40];

    const int tid  = threadIdx.x;
    const int lane = tid & 63;
    const int wid  = tid >> 6;
    const int wr = wid >> 1, wc = wid & 1;
    const int lr = lane & 15, lg = lane >> 4;

    f32x4 acc[4][4];
#pragma unroll
    for (int i = 0; i < 4; ++i)
#pragma unroll
        for (int j = 0; j < 4; ++j)
            acc[i][j] = (f32x4)0.0f;

    {
        float4 wv[4], xv[4];
        load_chunk(Wg, xb, K, dbase, i0, 0, tid, wv, xv);
        write_chunk(Wl[0], Xl[0], tid, wv, xv);
    }
    __syncthreads();

    for (int c = 0; c < nch; ++c) {
        const int cur = c & 1;
        float4 wv[4], xv[4];
        const bool pf = (c + 1 < nch);
        if (pf) load_chunk(Wg, xb, K, dbase, i0, (c + 1) << 5, tid, wv, xv);

        short8 af[4], bfr[4];
#pragma unroll
        for (int mi = 0; mi < 4; ++mi)
            af[mi] = *(const short8*)&Wl[cur][wr * 64 + mi * 16 + lr][lg * 8];
#pragma unroll
        for (int ni = 0; ni < 4; ++ni)
            bfr[ni] = *(const short8*)&Xl[cur][wc * 64 + ni * 16 + lr][lg * 8];
#pragma unroll
        for (int mi = 0; mi < 4; ++mi)
#pragma unroll
            for (int ni = 0; ni < 4; ++ni)
                acc[mi][ni] = __builtin_amdgcn_mfma_f32_16x16x32_bf16(af[mi], bfr[ni], acc[mi][ni], 0, 0, 0);

        if (pf) write_chunk(Wl[cur ^ 1], Xl[cur ^ 1], tid, wv, xv);
        __syncthreads();
    }

    const int ob = b * 768 + br * 256;
#pragma unroll
    for (int mi = 0; mi < 4; ++mi) {
#pragma unroll
        for (int rI = 0; rI < 4; ++rI) {
            const int d = dbase + wr * 64 + mi * 16 + lg * 4 + rI;
            const float bv = bg[d];
            float m = 0.f;
#pragma unroll
            for (int ni = 0; ni < 4; ++ni) {
                int win = i0 + wc * 64 + ni * 16 + lr;
                float v = acc[mi][ni][rI] + bv;
                v = fmaxf(v, 0.f);
                if (win >= Nw) v = 0.f;
                m = fmaxf(m, v);
            }
#pragma unroll
            for (int off = 1; off < 16; off <<= 1)
                m = fmaxf(m, __shfl_xor(m, off));
            if (lr == 0)
                atomicMax((int*)(out + ob + d), __float_as_int(m));
        }
    }
}

// ---------------- launch ----------------

extern "C" void kernel_launch(void* const* d_in, const int* in_sizes, int n_in,
                              void* d_out, int out_size, void* d_ws, size_t ws_size,
                              hipStream_t stream) {
    const float* x  = (const float*)d_in[0];
    const float* W1 = (const float*)d_in[1];
    const float* W2 = (const float*)d_in[2];
    const float* W3 = (const float*)d_in[3];
    const float* b1 = (const float*)d_in[4];
    const float* b2 = (const float*)d_in[5];
    const float* b3 = (const float*)d_in[6];
    float* out = (float*)d_out;

    hipMemsetAsync(d_out, 0, (size_t)out_size * sizeof(float), stream);

    const long WBTOT = WGRAN * 8;                        // 966,656 elems
    const size_t need = (size_t)(XPTOT + WBTOT) * 2;     // ~16.9 MB

    if (ws_size >= need) {
        unsigned short* xp = (unsigned short*)d_ws;
        unsigned short* wbb = xp + XPTOT;

        pack_x_kernel<<<7683, 256, 0, stream>>>(x, xp);          // 1,966,848/256 exact
        pack_w_kernel<<<472, 256, 0, stream>>>(W1, W2, W3, wbb); // 120,832/256 exact
        convgemm_kernel<<<256, 512, 0, stream>>>(xp, wbb, b1, b2, b3, out);
    } else {
        dim3 grid(64, 8, 3);
        convmax_fallback<<<grid, 256, 0, stream>>>(x, W1, W2, W3, b1, b2, b3, out);
    }
}